// Round 4
// baseline (486.408 us; speedup 1.0000x reference)
//
#include <hip/hip_runtime.h>
#include <stdint.h>

// Problem constants
#define NBATCH 2
#define NVERT  30000
#define VOLCH  16777216ull   // 64^3 * 64 elements per batch, layout (z,y,x,c)
#define KDIM   1728          // 27 * 64
#define ASTR   (KDIM + 8)    // row stride 1736 (x2B = 3472, 16B-aligned)

typedef __attribute__((ext_vector_type(8))) __bf16 bf16x8;
typedef __attribute__((ext_vector_type(4))) float f32x4;

__device__ __forceinline__ float b2f(unsigned short u) {
  unsigned int x = ((unsigned int)u) << 16;
  return __builtin_bit_cast(float, x);
}

__device__ __forceinline__ unsigned short f2b(float f) {
  unsigned int u = __builtin_bit_cast(unsigned int, f);
  u = (u + 0x7FFFu + ((u >> 16) & 1u)) >> 16;   // RNE (no NaN in this data)
  return (unsigned short)u;
}

// async global->LDS, 16B per lane; LDS dest = wave-uniform base + lane*16
__device__ __forceinline__ void gload_lds16(const unsigned short* g,
                                            unsigned short* l) {
  __builtin_amdgcn_global_load_lds(
      (const __attribute__((address_space(1))) void*)g,
      (__attribute__((address_space(3))) void*)l, 16, 0, 0);
}

// ---------------------------------------------------------------------------
// Kernel 1: transpose volume (b,c,z,y,x) f32 -> (b,z,y,x,c) bf16 in d_ws.
// 4 zy-rows per block; float4 reads (1KB/wave), ushort4 writes (512B/wave).
// tile padded [65][66]: zyq stride 8580B (+1 bank), c stride 132B (+1 bank).
// ---------------------------------------------------------------------------
__global__ __launch_bounds__(256) void transpose_vox(
    const float* __restrict__ vox, unsigned short* __restrict__ T) {
  __shared__ unsigned short tile[4][65][66];
  const int b = blockIdx.y;
  const int zy0 = blockIdx.x * 4;
  const int t = threadIdx.x;
  const size_t src0 = (size_t)b * 64 * 262144 + (size_t)zy0 * 64;
#pragma unroll
  for (int i = 0; i < 16; ++i) {
    const int idx = i * 256 + t;
    const int c = idx >> 6;
    const int rem = idx & 63;
    const int zyq = rem >> 4;
    const int x4 = (rem & 15) << 2;
    const float4 v = *reinterpret_cast<const float4*>(
        vox + src0 + (size_t)c * 262144 + zyq * 64 + x4);
    tile[zyq][c][x4 + 0] = f2b(v.x); tile[zyq][c][x4 + 1] = f2b(v.y);
    tile[zyq][c][x4 + 2] = f2b(v.z); tile[zyq][c][x4 + 3] = f2b(v.w);
  }
  __syncthreads();
  const size_t dst0 = ((size_t)b * 4096 + zy0) * 4096;
#pragma unroll
  for (int i = 0; i < 16; ++i) {
    const int idx = i * 256 + t;
    const int c4 = (idx & 15) << 2;
    const int pr = idx >> 4;                 // (zyq, x)
    const int zyq = pr >> 6;
    const int x = pr & 63;
    ushort4 o;
    o.x = tile[zyq][c4 + 0][x]; o.y = tile[zyq][c4 + 1][x];
    o.z = tile[zyq][c4 + 2][x]; o.w = tile[zyq][c4 + 3][x];
    *reinterpret_cast<ushort4*>(T + dst0 + ((size_t)zyq * 64 + x) * 64 + c4) = o;
  }
}

// ---------------------------------------------------------------------------
// Kernel 2: pack conv_w (o,c,k) f32 -> fragment-major bf16 W3[K>>3][o][K&7],
// K = k*64 + c.
// ---------------------------------------------------------------------------
__global__ __launch_bounds__(256) void prep_w(
    const float* __restrict__ w, unsigned short* __restrict__ W3) {
  int t = blockIdx.x * 256 + threadIdx.x;       // 432*256 == 110592 exactly
  int o = t / 1728;
  int rem = t - o * 1728;
  int c = rem / 27;
  int k = rem - c * 27;
  int K = k * 64 + c;
  W3[((size_t)(K >> 3) * 64 + o) * 8 + (K & 7)] = f2b(w[t]);
}

// ---------------------------------------------------------------------------
// Axis helpers. All arrays indexed with compile-time constants only.
// ---------------------------------------------------------------------------
struct Idx3 {        // element offsets into T for the 4 region positions/axis
  int x0, x1, x2, x3;    // *64
  int y0, y1, y2, y3;    // *4096
  int z0, z1, z2, z3;    // *262144
};

__device__ __forceinline__ int clamp63(int q) { return min(max(q, 0), 63); }

__device__ __forceinline__ int axis_b0(float v) {
  float coord = fminf(fmaxf((v + 1.0f) * 0.5f * 63.0f, 0.0f), 63.0f);
  int b0 = (int)coord;
  return min(b0, 63);
}

__device__ __forceinline__ Idx3 make_idx(float vx, float vy, float vz) {
  Idx3 I;
  int bx = axis_b0(vx), by = axis_b0(vy), bz = axis_b0(vz);
  I.x0 = clamp63(bx - 1) << 6;  I.x1 = clamp63(bx) << 6;
  I.x2 = clamp63(bx + 1) << 6;  I.x3 = clamp63(bx + 2) << 6;
  I.y0 = clamp63(by - 1) << 12; I.y1 = clamp63(by) << 12;
  I.y2 = clamp63(by + 1) << 12; I.y3 = clamp63(by + 2) << 12;
  I.z0 = clamp63(bz - 1) << 18; I.z1 = clamp63(bz) << 18;
  I.z2 = clamp63(bz + 1) << 18; I.z3 = clamp63(bz + 2) << 18;
  return I;
}

struct W12 { float x[3][4], y[3][4], z[3][4]; };

__device__ __forceinline__ void axis_w(float v, float gw[3][4]) {
  float coord = fminf(fmaxf((v + 1.0f) * 0.5f * 63.0f, 0.0f), 63.0f);
  int b0 = min((int)coord, 63);
#pragma unroll
  for (int d = 0; d < 3; ++d) {
    float tc = fminf(fmaxf(coord + (float)(d - 1), 0.0f), 63.0f);
    float fl = floorf(tc);
    int i0 = min((int)fl, 63);
    float f = tc - fl;
    int i1 = min(i0 + 1, 63);
    int p0 = i0 - b0 + 1;                       // in [0,3]
    int p1 = i1 - b0 + 1;
#pragma unroll
    for (int p = 0; p < 4; ++p) {
      float g = (p == p0) ? (1.0f - f) : 0.0f;
      g += (p == p1) ? f : 0.0f;
      gw[d][p] = g;
    }
  }
}

__device__ __forceinline__ W12 make_w(float vx, float vy, float vz) {
  W12 W;
  axis_w(vx, W.x); axis_w(vy, W.y); axis_w(vz, W.z);
  return W;
}

// issue one half-region (2 z-slices = 32 voxels = 4KB) as 4 global_load_lds.
// per instruction: lane = (y-parity<<5) | px<<3 | chunk -> 2y x 4x x 64c.
__device__ __forceinline__ void issue_half(
    const unsigned short* Tbase, int zA, int zB, int y_even, int y_odd,
    int xo_lane, unsigned short* rawX) {
  gload_lds16(Tbase + zA + y_even + xo_lane, rawX + 0 * 512);
  gload_lds16(Tbase + zA + y_odd  + xo_lane, rawX + 1 * 512);
  gload_lds16(Tbase + zB + y_even + xo_lane, rawX + 2 * 512);
  gload_lds16(Tbase + zB + y_odd  + xo_lane, rawX + 3 * 512);
}

// fold one half-region (pz slices 2H, 2H+1) from LDS raw into fe.
// raw layout: ushort idx = seg*512 + yhi*256 + px*64 + c, seg = z*2 + ypair.
template <int H>
__device__ __forceinline__ void fold_half(
    const unsigned short* rawX, const W12& W, float fe[3][3][3], int lane) {
#pragma unroll
  for (int pzh = 0; pzh < 2; ++pzh) {
    const int pz = 2 * H + pzh;
    float ry[3][3];
#pragma unroll
    for (int a = 0; a < 3; ++a)
#pragma unroll
      for (int b = 0; b < 3; ++b) ry[a][b] = 0.0f;
#pragma unroll
    for (int py = 0; py < 4; ++py) {
      const unsigned short* rp = rawX + ((pzh * 16 + py * 4) << 6) + lane;
      float v0 = b2f(rp[0]);
      float v1 = b2f(rp[64]);
      float v2 = b2f(rp[128]);
      float v3 = b2f(rp[192]);
      const float wy0 = W.y[0][py], wy1 = W.y[1][py], wy2 = W.y[2][py];
#pragma unroll
      for (int dx = 0; dx < 3; ++dx) {
        float rx = v0 * W.x[dx][0] + v1 * W.x[dx][1] +
                   v2 * W.x[dx][2] + v3 * W.x[dx][3];
        ry[0][dx] += rx * wy0;
        ry[1][dx] += rx * wy1;
        ry[2][dx] += rx * wy2;
      }
    }
#pragma unroll
    for (int dz = 0; dz < 3; ++dz) {
      const float wz = W.z[dz][pz];
#pragma unroll
      for (int dy = 0; dy < 3; ++dy)
#pragma unroll
        for (int dx = 0; dx < 3; ++dx) fe[dz][dy][dx] += ry[dy][dx] * wz;
    }
  }
}

// ---------------------------------------------------------------------------
// Kernel 3 (fused): 256 thr / 4 waves / 8 vertices per block. Per wave:
// 2 vertices; 4x4x4 region gathered via coalesced global_load_lds (1KB/inst)
// into private double-buffered LDS raw, counted vmcnt(4) pipeline, separable
// trilinear fold, A_lds staging, then per-wave 16-col o-tile MFMA (M=8 valid).
// LDS: A 27.8KB + raw 32KB = 60.5KB -> 2 blocks/CU.
// ---------------------------------------------------------------------------
__global__ __launch_bounds__(256) void fused_main(
    const float* __restrict__ verts, const unsigned short* __restrict__ T,
    const unsigned short* __restrict__ W3, const float* __restrict__ bias,
    float* __restrict__ out) {
  __shared__ __align__(16) unsigned short A_lds[8][ASTR];    // 27,776 B
  __shared__ __align__(16) unsigned short raw[4][2][2048];   // 32,768 B
  const int tid = threadIdx.x;
  const int wave = tid >> 6;                    // 0..3
  const int lane = tid & 63;
  const int batch = blockIdx.y;
  const int n0 = blockIdx.x * 8;

  const unsigned short* Tbase = T + (size_t)batch * VOLCH;
  unsigned short* rawA = &raw[wave][0][0];
  unsigned short* rawB = &raw[wave][1][0];
  const int m0 = wave * 2;

  // vertex coords for this wave's 2 vertices
  const size_t vb = ((size_t)batch * NVERT + (n0 + m0)) * 3;
  const float ax = verts[vb + 0], ay = verts[vb + 1], az = verts[vb + 2];
  const float bx = verts[vb + 3], by = verts[vb + 4], bz = verts[vb + 5];

  // per-lane invariant pieces
  const int ce = (lane & 7) << 3;               // channel chunk (elements)
  const int px = (lane >> 3) & 3;               // x region position

  // ---- vertex A: issue both halves ----
  const Idx3 IA = make_idx(ax, ay, az);
  const int xoA = (px & 2 ? (px & 1 ? IA.x3 : IA.x2)
                          : (px & 1 ? IA.x1 : IA.x0)) + ce;
  const int yeA = (lane & 32) ? IA.y1 : IA.y0;
  const int yoA = (lane & 32) ? IA.y3 : IA.y2;
  issue_half(Tbase, IA.z0, IA.z1, yeA, yoA, xoA, rawA);   // 4 outstanding
  issue_half(Tbase, IA.z2, IA.z3, yeA, yoA, xoA, rawB);   // 8 outstanding

  const W12 WA = make_w(ax, ay, az);
  const Idx3 IB = make_idx(bx, by, bz);
  const int xoB = (px & 2 ? (px & 1 ? IB.x3 : IB.x2)
                          : (px & 1 ? IB.x1 : IB.x0)) + ce;
  const int yeB = (lane & 32) ? IB.y1 : IB.y0;
  const int yoB = (lane & 32) ? IB.y3 : IB.y2;

  float fe[3][3][3];
#pragma unroll
  for (int a = 0; a < 3; ++a)
#pragma unroll
    for (int b = 0; b < 3; ++b)
#pragma unroll
      for (int c = 0; c < 3; ++c) fe[a][b][c] = 0.0f;

  asm volatile("s_waitcnt vmcnt(4)" ::: "memory");        // A half0 landed
  fold_half<0>(rawA, WA, fe, lane);
  issue_half(Tbase, IB.z0, IB.z1, yeB, yoB, xoB, rawA);   // B half0
  asm volatile("s_waitcnt vmcnt(4)" ::: "memory");        // A half1 landed
  fold_half<1>(rawB, WA, fe, lane);
  issue_half(Tbase, IB.z2, IB.z3, yeB, yoB, xoB, rawB);   // B half1

  // write vertex A feats: K = k*64 + c, k = dx*9 + dy*3 + dz
  {
    unsigned short* arow = &A_lds[m0][0];
#pragma unroll
    for (int dz = 0; dz < 3; ++dz)
#pragma unroll
      for (int dy = 0; dy < 3; ++dy)
#pragma unroll
        for (int dx = 0; dx < 3; ++dx) {
          int k = dx * 9 + dy * 3 + dz;
          arow[(k << 6) + lane] = f2b(fe[dz][dy][dx]);
        }
  }

  const W12 WB = make_w(bx, by, bz);
  float fe2[3][3][3];
#pragma unroll
  for (int a = 0; a < 3; ++a)
#pragma unroll
    for (int b = 0; b < 3; ++b)
#pragma unroll
      for (int c = 0; c < 3; ++c) fe2[a][b][c] = 0.0f;

  asm volatile("s_waitcnt vmcnt(4)" ::: "memory");        // B half0 landed
  fold_half<0>(rawA, WB, fe2, lane);
  asm volatile("s_waitcnt vmcnt(0)" ::: "memory");        // B half1 landed
  fold_half<1>(rawB, WB, fe2, lane);
  {
    unsigned short* arow = &A_lds[m0 + 1][0];
#pragma unroll
    for (int dz = 0; dz < 3; ++dz)
#pragma unroll
      for (int dy = 0; dy < 3; ++dy)
#pragma unroll
        for (int dx = 0; dx < 3; ++dx) {
          int k = dx * 9 + dy * 3 + dz;
          arow[(k << 6) + lane] = f2b(fe2[dz][dy][dx]);
        }
  }
  __syncthreads();

  // ---- phase 2: per-wave o-tile MFMA over full K. M rows 0..7 valid
  // (r>=8 duplicates row r-8, results discarded). ----
  const int g = lane >> 4;
  const int r = lane & 15;
  const int o0 = wave * 16;
  f32x4 acc = {0.0f, 0.0f, 0.0f, 0.0f};
  const unsigned short* aptr = &A_lds[r & 7][g * 8];
  const unsigned short* bptr = W3 + (size_t)(g * 64 + o0 + r) * 8;
#pragma unroll 1
  for (int kk = 0; kk < 54; ++kk) {
    bf16x8 a = *reinterpret_cast<const bf16x8*>(aptr + kk * 32);
    bf16x8 b = *reinterpret_cast<const bf16x8*>(bptr + (size_t)kk * 2048);
    acc = __builtin_amdgcn_mfma_f32_16x16x32_bf16(a, b, acc, 0, 0, 0);
  }

  // epilogue: D col = r (o), row = g*4 + i (vertex); rows 0..7 only (g<2)
  const int oc = o0 + r;
  const float bo = bias[oc];
  if (g < 2) {
    float* op = out + ((size_t)batch * NVERT + n0) * 64 + oc;
#pragma unroll
    for (int i = 0; i < 4; ++i) {
      op[(size_t)(g * 4 + i) * 64] = acc[i] + bo;
    }
  }
}

extern "C" void kernel_launch(void* const* d_in, const int* in_sizes, int n_in,
                              void* d_out, int out_size, void* d_ws, size_t ws_size,
                              hipStream_t stream) {
  const float* vox   = (const float*)d_in[0];
  const float* verts = (const float*)d_in[1];
  const float* convw = (const float*)d_in[2];
  const float* convb = (const float*)d_in[3];
  float* out = (float*)d_out;

  const size_t t_elems = (size_t)NBATCH * VOLCH;        // 33,554,432 bf16
  const size_t need = t_elems * 2 + (size_t)110592 * 2; // ~67.3 MB
  if (ws_size < need) {
    hipMemsetAsync(d_out, 0xFF, (size_t)out_size * 4, stream);
    return;
  }
  unsigned short* T  = (unsigned short*)d_ws;
  unsigned short* W3 = T + t_elems;

  transpose_vox<<<dim3(1024, NBATCH), 256, 0, stream>>>(vox, T);
  prep_w<<<432, 256, 0, stream>>>(convw, W3);
  fused_main<<<dim3(NVERT / 8, NBATCH), 256, 0, stream>>>(verts, T, W3, convb, out);
}

// Round 5
// 446.374 us; speedup vs baseline: 1.0897x; 1.0897x over previous
//
#include <hip/hip_runtime.h>
#include <stdint.h>

// Problem constants
#define NBATCH 2
#define NVERT  30000
#define VOLCH  16777216ull   // 64^3 * 64 elements per batch, layout (z,y,x,c)
#define KDIM   1728          // 27 * 64
#define ASTR   (KDIM + 8)    // row stride 1736 (x2B = 3472, 16B-aligned)
#define NBINS  512

typedef __attribute__((ext_vector_type(8))) __bf16 bf16x8;
typedef __attribute__((ext_vector_type(4))) float f32x4;

__device__ __forceinline__ float b2f(unsigned short u) {
  unsigned int x = ((unsigned int)u) << 16;
  return __builtin_bit_cast(float, x);
}

__device__ __forceinline__ unsigned short f2b(float f) {
  unsigned int u = __builtin_bit_cast(unsigned int, f);
  u = (u + 0x7FFFu + ((u >> 16) & 1u)) >> 16;   // RNE (no NaN in this data)
  return (unsigned short)u;
}

// ---------------------------------------------------------------------------
// Kernel 1: transpose volume (b,c,z,y,x) f32 -> (b,z,y,x,c) bf16 in d_ws.
// ---------------------------------------------------------------------------
__global__ __launch_bounds__(256) void transpose_vox(
    const float* __restrict__ vox, unsigned short* __restrict__ T) {
  __shared__ unsigned short tile[4][65][66];
  const int b = blockIdx.y;
  const int zy0 = blockIdx.x * 4;
  const int t = threadIdx.x;
  const size_t src0 = (size_t)b * 64 * 262144 + (size_t)zy0 * 64;
#pragma unroll
  for (int i = 0; i < 16; ++i) {
    const int idx = i * 256 + t;
    const int c = idx >> 6;
    const int rem = idx & 63;
    const int zyq = rem >> 4;
    const int x4 = (rem & 15) << 2;
    const float4 v = *reinterpret_cast<const float4*>(
        vox + src0 + (size_t)c * 262144 + zyq * 64 + x4);
    tile[zyq][c][x4 + 0] = f2b(v.x); tile[zyq][c][x4 + 1] = f2b(v.y);
    tile[zyq][c][x4 + 2] = f2b(v.z); tile[zyq][c][x4 + 3] = f2b(v.w);
  }
  __syncthreads();
  const size_t dst0 = ((size_t)b * 4096 + zy0) * 4096;
#pragma unroll
  for (int i = 0; i < 16; ++i) {
    const int idx = i * 256 + t;
    const int c4 = (idx & 15) << 2;
    const int pr = idx >> 4;                 // (zyq, x)
    const int zyq = pr >> 6;
    const int x = pr & 63;
    ushort4 o;
    o.x = tile[zyq][c4 + 0][x]; o.y = tile[zyq][c4 + 1][x];
    o.z = tile[zyq][c4 + 2][x]; o.w = tile[zyq][c4 + 3][x];
    *reinterpret_cast<ushort4*>(T + dst0 + ((size_t)zyq * 64 + x) * 64 + c4) = o;
  }
}

// ---------------------------------------------------------------------------
// Kernel 2: pack conv_w (o,c,k) f32 -> fragment-major bf16 W3[K>>3][o][K&7],
// K = k*64 + c.
// ---------------------------------------------------------------------------
__global__ __launch_bounds__(256) void prep_w(
    const float* __restrict__ w, unsigned short* __restrict__ W3) {
  int t = blockIdx.x * 256 + threadIdx.x;       // 432*256 == 110592 exactly
  int o = t / 1728;
  int rem = t - o * 1728;
  int c = rem / 27;
  int k = rem - c * 27;
  int K = k * 64 + c;
  W3[((size_t)(K >> 3) * 64 + o) * 8 + (K & 7)] = f2b(w[t]);
}

// ---------------------------------------------------------------------------
// Axis helpers
// ---------------------------------------------------------------------------
__device__ __forceinline__ int axis_b0(float v) {
  float coord = fminf(fmaxf((v + 1.0f) * 0.5f * 63.0f, 0.0f), 63.0f);
  int b0 = (int)coord;
  return min(b0, 63);
}

__device__ __forceinline__ void axis_setup(float v, int idx[4], float gw[3][4]) {
  float coord = fminf(fmaxf((v + 1.0f) * 0.5f * 63.0f, 0.0f), 63.0f);
  int b0 = min((int)coord, 63);
#pragma unroll
  for (int p = 0; p < 4; ++p) {
    int q = b0 - 1 + p;
    idx[p] = min(max(q, 0), 63);
  }
#pragma unroll
  for (int d = 0; d < 3; ++d) {
    float tc = fminf(fmaxf(coord + (float)(d - 1), 0.0f), 63.0f);
    float fl = floorf(tc);
    int i0 = min((int)fl, 63);
    float f = tc - fl;
    int i1 = min(i0 + 1, 63);
    int p0 = i0 - b0 + 1;                       // in [0,3]
    int p1 = i1 - b0 + 1;
#pragma unroll
    for (int p = 0; p < 4; ++p) {
      float g = (p == p0) ? (1.0f - f) : 0.0f;
      g += (p == p1) ? f : 0.0f;
      gw[d][p] = g;
    }
  }
}

// ---------------------------------------------------------------------------
// Binning: counting sort of vertices by (z, y-band) for L2 locality.
// bin = (bz<<3) | (by>>3): 512 bins. Output identical regardless of atomic
// ordering (each vertex computed independently, written to its own row).
// ---------------------------------------------------------------------------
__device__ __forceinline__ int vert_bin(const float* p) {
  return (axis_b0(p[2]) << 3) | (axis_b0(p[1]) >> 3);
}

__global__ __launch_bounds__(256) void binhist(
    const float* __restrict__ verts, int* __restrict__ hist) {
  int t = blockIdx.x * 256 + threadIdx.x;
  if (t >= NBATCH * NVERT) return;
  int b = t / NVERT;
  atomicAdd(&hist[b * NBINS + vert_bin(verts + (size_t)t * 3)], 1);
}

__global__ __launch_bounds__(512) void binscan(
    const int* __restrict__ hist, int* __restrict__ off) {
  __shared__ int s0[NBINS], s1[NBINS];
  const int t = threadIdx.x;
#pragma unroll 1
  for (int b = 0; b < NBATCH; ++b) {
    const int orig = hist[b * NBINS + t];
    s0[t] = orig;
    __syncthreads();
    int* src = s0;
    int* dst = s1;
#pragma unroll 1
    for (int o = 1; o < NBINS; o <<= 1) {
      int v = src[t] + ((t >= o) ? src[t - o] : 0);
      dst[t] = v;
      __syncthreads();
      int* tmp = src; src = dst; dst = tmp;
    }
    off[b * NBINS + t] = src[t] - orig;         // exclusive prefix
    __syncthreads();
  }
}

__global__ __launch_bounds__(256) void binscat(
    const float* __restrict__ verts, int* __restrict__ off,
    int* __restrict__ perm) {
  int t = blockIdx.x * 256 + threadIdx.x;
  if (t >= NBATCH * NVERT) return;
  int b = t / NVERT;
  int v = t - b * NVERT;
  int bin = vert_bin(verts + (size_t)t * 3);
  int pos = atomicAdd(&off[b * NBINS + bin], 1);
  perm[b * NVERT + pos] = v;
}

// ---------------------------------------------------------------------------
// Kernel 3 (fused): 256 thr / 4 waves / 16 binned vertices per block.
// Phase 1: wave w folds vertices 4w..4w+3 (lane = channel) -> A_lds.
// Phase 2: per-wave 16-col o-tile MFMA over full K (M=16).
// Blocks XCD-chunk-swizzled so each XCD's L2 sees a contiguous bin range.
// LDS 55.6KB -> 2 blocks/CU.
// ---------------------------------------------------------------------------
__global__ __launch_bounds__(256) void fused_main(
    const float* __restrict__ verts, const unsigned short* __restrict__ T,
    const unsigned short* __restrict__ W3, const float* __restrict__ bias,
    const int* __restrict__ perm, float* __restrict__ out) {
  __shared__ __align__(16) unsigned short A_lds[16][ASTR];   // 55,552 B
  __shared__ int pvid[16];
  const int tid = threadIdx.x;
  const int wave = tid >> 6;
  const int lane = tid & 63;

  // bijective XCD-chunked swizzle (m204): NWG=3750, q=468, r=6
  const int orig = blockIdx.x;
  const int xcd = orig & 7;
  const int j = orig >> 3;
  const int wg = (xcd < 6 ? xcd * 469 : 6 * 469 + (xcd - 6) * 468) + j;
  const int batch = wg / 1875;
  const int n0 = (wg - batch * 1875) * 16;

  if (tid < 16) pvid[tid] = perm[batch * NVERT + n0 + tid];
  __syncthreads();

  const unsigned short* Tb = T + (size_t)batch * VOLCH + lane;  // lane = channel

  // ---- phase 1: gather + separable trilinear fold (4 vertices per wave) ----
#pragma unroll 1
  for (int vl = 0; vl < 4; ++vl) {
    const int m = wave * 4 + vl;
    const int vid = pvid[m];
    const size_t vbase = ((size_t)batch * NVERT + vid) * 3;
    const float vx = verts[vbase + 0];
    const float vy = verts[vbase + 1];
    const float vz = verts[vbase + 2];

    int xi[4], yi[4], zi[4];
    float gwx[3][4], gwy[3][4], gwz[3][4];
    axis_setup(vx, xi, gwx);
    axis_setup(vy, yi, gwy);
    axis_setup(vz, zi, gwz);

    int xo[4];
#pragma unroll
    for (int p = 0; p < 4; ++p) xo[p] = xi[p] << 6;   // *64 channels

    float fe[3][3][3];
#pragma unroll
    for (int a = 0; a < 3; ++a)
#pragma unroll
      for (int bb = 0; bb < 3; ++bb)
#pragma unroll
        for (int cc = 0; cc < 3; ++cc) fe[a][bb][cc] = 0.0f;

#pragma unroll
    for (int pz = 0; pz < 4; ++pz) {
      float ryv[3][3];
#pragma unroll
      for (int a = 0; a < 3; ++a)
#pragma unroll
        for (int bb = 0; bb < 3; ++bb) ryv[a][bb] = 0.0f;
      const int zoff = zi[pz] << 18;                  // *64*64*64
#pragma unroll
      for (int py = 0; py < 4; ++py) {
        const unsigned short* rp = Tb + zoff + (yi[py] << 12);
        float v0 = b2f(rp[xo[0]]);                    // 128B coalesced per voxel
        float v1 = b2f(rp[xo[1]]);
        float v2 = b2f(rp[xo[2]]);
        float v3 = b2f(rp[xo[3]]);
        const float wy0 = gwy[0][py], wy1 = gwy[1][py], wy2 = gwy[2][py];
#pragma unroll
        for (int dx = 0; dx < 3; ++dx) {
          float rx = v0 * gwx[dx][0] + v1 * gwx[dx][1] +
                     v2 * gwx[dx][2] + v3 * gwx[dx][3];
          ryv[0][dx] += rx * wy0;
          ryv[1][dx] += rx * wy1;
          ryv[2][dx] += rx * wy2;
        }
      }
#pragma unroll
      for (int dz = 0; dz < 3; ++dz) {
        const float wz = gwz[dz][pz];
#pragma unroll
        for (int dy = 0; dy < 3; ++dy)
#pragma unroll
          for (int dx = 0; dx < 3; ++dx) fe[dz][dy][dx] += ryv[dy][dx] * wz;
      }
    }

    // write feats, K = k*64 + c with k = dx*9 + dy*3 + dz (product order)
    unsigned short* arow = &A_lds[m][0];
#pragma unroll
    for (int dz = 0; dz < 3; ++dz)
#pragma unroll
      for (int dy = 0; dy < 3; ++dy)
#pragma unroll
        for (int dx = 0; dx < 3; ++dx) {
          int k = dx * 9 + dy * 3 + dz;
          arow[(k << 6) + lane] = f2b(fe[dz][dy][dx]);  // contiguous across lanes
        }
  }
  __syncthreads();

  // ---- phase 2: MFMA GEMM, one 16x16 o-tile per wave, M=16 vertices ----
  const int g = lane >> 4;                      // k-group 0..3
  const int r = lane & 15;                      // A-row / B-col index
  const int o0 = wave * 16;
  f32x4 acc = {0.0f, 0.0f, 0.0f, 0.0f};
  const unsigned short* aptr = &A_lds[r][g * 8];
  const unsigned short* bptr = W3 + (size_t)(g * 64 + o0 + r) * 8;
#pragma unroll 1
  for (int kk = 0; kk < 54; ++kk) {
    bf16x8 a = *reinterpret_cast<const bf16x8*>(aptr + kk * 32);
    bf16x8 b = *reinterpret_cast<const bf16x8*>(bptr + (size_t)kk * 2048);
    acc = __builtin_amdgcn_mfma_f32_16x16x32_bf16(a, b, acc, 0, 0, 0);
  }

  // epilogue: D col = r (o), row = g*4+i (vertex slot); scatter to perm row
  const int oc = o0 + r;
  const float bo = bias[oc];
#pragma unroll
  for (int i = 0; i < 4; ++i) {
    const int row = g * 4 + i;
    const int vid = pvid[row];
    out[((size_t)batch * NVERT + vid) * 64 + oc] = acc[i] + bo;
  }
}

extern "C" void kernel_launch(void* const* d_in, const int* in_sizes, int n_in,
                              void* d_out, int out_size, void* d_ws, size_t ws_size,
                              hipStream_t stream) {
  const float* vox   = (const float*)d_in[0];
  const float* verts = (const float*)d_in[1];
  const float* convw = (const float*)d_in[2];
  const float* convb = (const float*)d_in[3];
  float* out = (float*)d_out;

  const size_t t_elems = (size_t)NBATCH * VOLCH;        // 33,554,432 bf16
  const size_t t_bytes = t_elems * 2;                   // 67,108,864
  const size_t w3_bytes = (size_t)110592 * 2;           // 221,184
  const size_t hist_bytes = (size_t)NBATCH * NBINS * 4; // 4,096
  const size_t off_bytes  = hist_bytes;
  const size_t perm_bytes = (size_t)NBATCH * NVERT * 4; // 240,000
  const size_t need = t_bytes + w3_bytes + hist_bytes + off_bytes + perm_bytes;
  if (ws_size < need) {
    hipMemsetAsync(d_out, 0xFF, (size_t)out_size * 4, stream);
    return;
  }
  unsigned short* T  = (unsigned short*)d_ws;
  unsigned short* W3 = T + t_elems;
  char* base = (char*)d_ws + t_bytes + w3_bytes;
  int* hist = (int*)base;
  int* off  = (int*)(base + hist_bytes);
  int* perm = (int*)(base + hist_bytes + off_bytes);

  hipMemsetAsync(hist, 0, hist_bytes, stream);
  transpose_vox<<<dim3(1024, NBATCH), 256, 0, stream>>>(vox, T);
  prep_w<<<432, 256, 0, stream>>>(convw, W3);
  binhist<<<(NBATCH * NVERT + 255) / 256, 256, 0, stream>>>(verts, hist);
  binscan<<<1, 512, 0, stream>>>(hist, off);
  binscat<<<(NBATCH * NVERT + 255) / 256, 256, 0, stream>>>(verts, off, perm);
  fused_main<<<3750, 256, 0, stream>>>(verts, T, W3, convb, perm, out);
}